// Round 2
// baseline (301.768 us; speedup 1.0000x reference)
//
#include <hip/hip_runtime.h>

// j = 1 - log10(1024*|x-y| + 1), elementwise over float32 tensors.
// shape (8,16,4096,64) = 33,554,432 f32 elements per tensor.
// Memory-bound: 12 bytes/elem total traffic (402 MB) -> ~64 us floor @6.3 TB/s.
// NOTE (R1 post-mortem): inputs/outputs are FLOAT32 per the reference
// (jnp.float32); the earlier bf16 assumption covered only half the buffer.

__device__ __forceinline__ float j_elem(float xv, float yv) {
    float d = xv - yv;
    // sqrt(1024^2 * d^2) == 1024 * |d|
    float dist = 1024.0f * fabsf(d);
    // log10(v) = log2(v) * log10(2); v_log_f32 accuracy ~1 ulp, threshold is 5.75e-2
    return 1.0f - 0.30102999566398120f * __log2f(dist + 1.0f);
}

__global__ __launch_bounds__(256) void j_vec4_kernel(const float4* __restrict__ x,
                                                     const float4* __restrict__ y,
                                                     float4* __restrict__ out,
                                                     int nvec) {
    int i = blockIdx.x * blockDim.x + threadIdx.x;
    if (i >= nvec) return;
    float4 xv = x[i];
    float4 yv = y[i];
    float4 ov;
    ov.x = j_elem(xv.x, yv.x);
    ov.y = j_elem(xv.y, yv.y);
    ov.z = j_elem(xv.z, yv.z);
    ov.w = j_elem(xv.w, yv.w);
    out[i] = ov;
}

__global__ __launch_bounds__(256) void j_tail_kernel(const float* __restrict__ x,
                                                     const float* __restrict__ y,
                                                     float* __restrict__ out,
                                                     int start, int n) {
    int i = start + blockIdx.x * blockDim.x + threadIdx.x;
    if (i >= n) return;
    out[i] = j_elem(x[i], y[i]);
}

extern "C" void kernel_launch(void* const* d_in, const int* in_sizes, int n_in,
                              void* d_out, int out_size, void* d_ws, size_t ws_size,
                              hipStream_t stream) {
    const int n = out_size;                  // 33,554,432 f32 elements
    const int nvec = n / 4;                  // 4 f32 per float4
    const int rem = n - nvec * 4;

    if (nvec > 0) {
        int blocks = (nvec + 255) / 256;
        j_vec4_kernel<<<blocks, 256, 0, stream>>>(
            (const float4*)d_in[0], (const float4*)d_in[1], (float4*)d_out, nvec);
    }
    if (rem > 0) {
        j_tail_kernel<<<1, 256, 0, stream>>>(
            (const float*)d_in[0], (const float*)d_in[1],
            (float*)d_out, nvec * 4, n);
    }
}